// Round 2
// baseline (604.869 us; speedup 1.0000x reference)
//
#include <hip/hip_runtime.h>
#include <math.h>

#define N_TOKENS 16384
#define DIM      4096
#define NE       64
#define TOPK     8
#define MT       64          // tokens per block
#define BK       32          // k-tile
#define LDP      68          // padded leading dim (floats): 16B-aligned rows, 2-way-max bank alias
#define KTILES   (DIM / BK)  // 128

__global__ __launch_bounds__(256) void router_kernel(
    const float* __restrict__ X,   // [16384, 4096]
    const float* __restrict__ W,   // [64, 4096]
    const float* __restrict__ B,   // [64]
    float* __restrict__ outP,      // [16384, 8]
    float* __restrict__ outI)      // [16384, 8] (indices stored as float)
{
    // Union LDS: during GEMM, As=[BK][LDP], Ws=[BK][LDP]; during epilogue, scores=[64][LDP]
    __shared__ float lds[2 * BK * LDP];   // 4352 floats = 17408 B
    float* As = lds;
    float* Ws = lds + BK * LDP;

    const int tid = threadIdx.x;
    const int tx  = tid & 15;   // expert group (4 experts each)
    const int ty  = tid >> 4;   // token group  (4 tokens each)
    const int m0  = blockIdx.x * MT;

    // Staging layout: 32 rows x 8 float4-cols per pass, 2 passes (rows 0..63)
    const int row = tid >> 3;   // 0..31
    const int col = tid & 7;    // 0..7

    const float* Aptr0 = X + (size_t)(m0 + row)      * DIM + col * 4;
    const float* Aptr1 = X + (size_t)(m0 + row + 32) * DIM + col * 4;
    const float* Wptr0 = W + (size_t)(row)           * DIM + col * 4;
    const float* Wptr1 = W + (size_t)(row + 32)      * DIM + col * 4;

    // fp64 accumulation: residual error ~ per-product rounding (~6e-8),
    // far below the fp32 refs' own ~1e-6 — prevents top-k boundary flips.
    double acc[4][4] = {};

    // prefetch tile 0
    float4 a0 = *(const float4*)(Aptr0);
    float4 a1 = *(const float4*)(Aptr1);
    float4 w0 = *(const float4*)(Wptr0);
    float4 w1 = *(const float4*)(Wptr1);

    for (int kt = 0; kt < KTILES; ++kt) {
        __syncthreads();   // prior tile's LDS reads done
        #pragma unroll
        for (int i = 0; i < 4; ++i) {
            As[(col * 4 + i) * LDP + row]      = ((const float*)&a0)[i];
            As[(col * 4 + i) * LDP + row + 32] = ((const float*)&a1)[i];
            Ws[(col * 4 + i) * LDP + row]      = ((const float*)&w0)[i];
            Ws[(col * 4 + i) * LDP + row + 32] = ((const float*)&w1)[i];
        }
        __syncthreads();

        // issue next tile's global loads; first use is after next barrier
        if (kt + 1 < KTILES) {
            const int off = (kt + 1) * BK;
            a0 = *(const float4*)(Aptr0 + off);
            a1 = *(const float4*)(Aptr1 + off);
            w0 = *(const float4*)(Wptr0 + off);
            w1 = *(const float4*)(Wptr1 + off);
        }

        #pragma unroll
        for (int k = 0; k < BK; ++k) {
            float4 av = *(const float4*)&As[k * LDP + ty * 4];
            float4 wv = *(const float4*)&Ws[k * LDP + tx * 4];
            double ad[4], wd[4];
            #pragma unroll
            for (int i = 0; i < 4; ++i) {
                ad[i] = (double)((const float*)&av)[i];
                wd[i] = (double)((const float*)&wv)[i];
            }
            #pragma unroll
            for (int i = 0; i < 4; ++i)
                #pragma unroll
                for (int j = 0; j < 4; ++j)
                    acc[i][j] = fma(ad[i], wd[j], acc[i][j]);
        }
    }

    // ---- epilogue: bias + scores into LDS (overlay) ----
    __syncthreads();   // all LDS GEMM reads complete before overwrite
    float4 bias = *(const float4*)(B + tx * 4);
    #pragma unroll
    for (int i = 0; i < 4; ++i)
        #pragma unroll
        for (int j = 0; j < 4; ++j)
            lds[(ty * 4 + i) * LDP + (tx * 4 + j)] =
                (float)(acc[i][j] + (double)((const float*)&bias)[j]);
    __syncthreads();

    // ---- top-8 + softmax: one wave per 16 tokens ----
    const int wave = tid >> 6;   // 0..3
    const int lane = tid & 63;

    for (int t16 = 0; t16 < 16; ++t16) {
        const int t = wave * 16 + t16;            // local token
        float sv = lds[t * LDP + lane];           // my expert's score
        float myv = 0.f; int myi = 0;
        float m0v = 0.f, sum = 0.f;

        #pragma unroll
        for (int k = 0; k < TOPK; ++k) {
            float rv = sv; int ri = lane;
            #pragma unroll
            for (int off = 32; off; off >>= 1) {
                float ov = __shfl_xor(rv, off);
                int   oi = __shfl_xor(ri, off);
                if (ov > rv || (ov == rv && oi < ri)) { rv = ov; ri = oi; }
            }
            // (rv, ri) uniform across wave: k-th largest, ties -> lowest index
            if (k == 0) m0v = rv;
            sum += expf(rv - m0v);
            if (lane == k) { myv = rv; myi = ri; }
            if (lane == ri) sv = -INFINITY;
        }

        if (lane < TOPK) {
            const size_t o = (size_t)(m0 + t) * TOPK + lane;
            outP[o] = expf(myv - m0v) / sum;
            outI[o] = (float)myi;
        }
    }
}

extern "C" void kernel_launch(void* const* d_in, const int* in_sizes, int n_in,
                              void* d_out, int out_size, void* d_ws, size_t ws_size,
                              hipStream_t stream) {
    const float* X = (const float*)d_in[0];
    const float* W = (const float*)d_in[1];
    const float* B = (const float*)d_in[2];
    float* outP = (float*)d_out;                       // [16384,8] probabilities
    float* outI = (float*)d_out + (size_t)N_TOKENS * TOPK;  // [16384,8] indices as float

    dim3 grid(N_TOKENS / MT);   // 256
    dim3 block(256);
    router_kernel<<<grid, block, 0, stream>>>(X, W, B, outP, outI);
}

// Round 3
// 446.696 us; speedup vs baseline: 1.3541x; 1.3541x over previous
//
#include <hip/hip_runtime.h>
#include <math.h>

#define NTOK 16384
#define DIM  4096
#define NE   64
#define TOPK 8
#define MT   64            // tokens per block
#define BK   64            // k-tile
#define KT   (DIM / BK)    // 64
#define NSEL 11            // candidates kept per token
#define EPS  1e-4f         // ambiguity threshold (our max err ~3e-5)
#define LDA  72            // bf16 row pitch (144 B, 16B-aligned, ~2-way banks)
#define LDSC 68            // score row pitch (floats)

typedef __attribute__((ext_vector_type(8))) short short8;   // 8 x bf16 frag
typedef __attribute__((ext_vector_type(4))) float f32x4;

__device__ __forceinline__ unsigned short f2bf(float f) {
    union { float f; unsigned u; } c; c.f = f;
    unsigned u = c.u + 0x7FFFu + ((c.u >> 16) & 1u);   // RNE
    return (unsigned short)(u >> 16);
}
__device__ __forceinline__ float bf2f(unsigned short h) {
    union { unsigned u; float f; } c; c.u = ((unsigned)h) << 16;
    return c.f;
}

#define CV1(H,L,I,V) { float _e=(V); unsigned short _h=f2bf(_e); H[I]=(short)_h; L[I]=(short)f2bf(_e-bf2f(_h)); }
#define CV8(H,L,A,Bq) CV1(H,L,0,(A).x) CV1(H,L,1,(A).y) CV1(H,L,2,(A).z) CV1(H,L,3,(A).w) \
                      CV1(H,L,4,(Bq).x) CV1(H,L,5,(Bq).y) CV1(H,L,6,(Bq).z) CV1(H,L,7,(Bq).w)

__global__ __launch_bounds__(256) void router_kernel(
    const float* __restrict__ X,   // [16384, 4096]
    const float* __restrict__ W,   // [64, 4096]
    const float* __restrict__ Bv,  // [64]
    float* __restrict__ outP,      // [16384, 8]
    float* __restrict__ outI)      // [16384, 8] indices as float
{
    // GEMM phase: Ah/Al/Wh/Wl bf16 tiles. Epilogue overlays scores S[64][68] f32.
    __shared__ __align__(16) unsigned short sm[4 * MT * LDA];   // 36864 B
    unsigned short* Ah = sm;
    unsigned short* Al = sm + MT * LDA;
    unsigned short* Wh = sm + 2 * MT * LDA;
    unsigned short* Wl = sm + 3 * MT * LDA;
    float* S = (float*)sm;

    const int tid  = threadIdx.x;
    const int m0   = blockIdx.x * MT;
    const int wvid = tid >> 6;        // wave 0..3 -> token rows 16w..16w+16
    const int lane = tid & 63;
    const int l15  = lane & 15;
    const int quad = lane >> 4;

    // staging map: 256 threads cover 64 rows x 64 k (16 floats each)
    const int srow = tid >> 2;        // 0..63
    const int scol = (tid & 3) << 4;  // 0,16,32,48

    const float* Xp = X + (size_t)(m0 + srow) * DIM + scol;
    const float* Wp = W + (size_t)srow * DIM + scol;

    f32x4 acc[4];
    acc[0] = acc[1] = acc[2] = acc[3] = (f32x4){0.f, 0.f, 0.f, 0.f};

    float4 xv[4], wv[4];
#pragma unroll
    for (int j = 0; j < 4; ++j) { xv[j] = *(const float4*)(Xp + j * 4); wv[j] = *(const float4*)(Wp + j * 4); }

    for (int kt = 0; kt < KT; ++kt) {
        __syncthreads();   // prior tile's LDS reads done
        // convert fp32 -> (hi,lo) bf16 and stage
        short8 xh0, xl0, xh1, xl1, wh0, wl0, wh1, wl1;
        CV8(xh0, xl0, xv[0], xv[1])
        CV8(xh1, xl1, xv[2], xv[3])
        CV8(wh0, wl0, wv[0], wv[1])
        CV8(wh1, wl1, wv[2], wv[3])
        const int sb = srow * LDA + scol;
        *(short8*)&Ah[sb]     = xh0;  *(short8*)&Ah[sb + 8] = xh1;
        *(short8*)&Al[sb]     = xl0;  *(short8*)&Al[sb + 8] = xl1;
        *(short8*)&Wh[sb]     = wh0;  *(short8*)&Wh[sb + 8] = wh1;
        *(short8*)&Wl[sb]     = wl0;  *(short8*)&Wl[sb + 8] = wl1;
        __syncthreads();

        // prefetch next tile into registers (consumed next iteration)
        if (kt + 1 < KT) {
            const float* xq = Xp + (kt + 1) * BK;
            const float* wq = Wp + (kt + 1) * BK;
#pragma unroll
            for (int j = 0; j < 4; ++j) { xv[j] = *(const float4*)(xq + j * 4); wv[j] = *(const float4*)(wq + j * 4); }
        }

        // MFMA: wave w computes token rows [16w,16w+16) x all 64 experts
#pragma unroll
        for (int ks = 0; ks < 2; ++ks) {
            const int ko = ks * 32 + quad * 8;
            const int ar = (wvid * 16 + l15) * LDA + ko;
            short8 a_h = *(const short8*)&Ah[ar];
            short8 a_l = *(const short8*)&Al[ar];
#pragma unroll
            for (int nt = 0; nt < 4; ++nt) {
                const int br = (nt * 16 + l15) * LDA + ko;
                short8 b_h = *(const short8*)&Wh[br];
                short8 b_l = *(const short8*)&Wl[br];
                acc[nt] = __builtin_amdgcn_mfma_f32_16x16x32_bf16(a_h, b_h, acc[nt], 0, 0, 0);
                acc[nt] = __builtin_amdgcn_mfma_f32_16x16x32_bf16(a_h, b_l, acc[nt], 0, 0, 0);
                acc[nt] = __builtin_amdgcn_mfma_f32_16x16x32_bf16(a_l, b_h, acc[nt], 0, 0, 0);
                acc[nt] = __builtin_amdgcn_mfma_f32_16x16x32_bf16(a_l, b_l, acc[nt], 0, 0, 0);
            }
        }
    }

    // ---- scores -> LDS overlay: S[e][tok], e-major so topk scan is conflict-free ----
    __syncthreads();
#pragma unroll
    for (int nt = 0; nt < 4; ++nt) {
        float bb = Bv[nt * 16 + l15];
#pragma unroll
        for (int r = 0; r < 4; ++r) {
            // C/D layout (m89): col(n)=lane&15, row(m)=quad*4+r
            const int m = wvid * 16 + quad * 4 + r;
            S[(nt * 16 + l15) * LDSC + m] = acc[nt][r] + bb;
        }
    }
    __syncthreads();
    if (wvid != 0) return;

    // ---- wave 0: lane = token. Scan 64 experts, keep top-11 (val desc, idx asc) ----
    float v[NSEL]; int id[NSEL];
#pragma unroll
    for (int j = 0; j < NSEL; ++j) { v[j] = -INFINITY; id[j] = 0; }
    for (int e = 0; e < NE; ++e) {
        float cv = S[e * LDSC + lane];
        int ci = e;
#pragma unroll
        for (int j = 0; j < NSEL; ++j) {
            bool gt = cv > v[j];     // strict: equal incoming (higher e) stays below
            float tv = gt ? v[j] : cv;
            int   ti = gt ? id[j] : ci;
            v[j]  = gt ? cv : v[j];
            id[j] = gt ? ci : id[j];
            cv = tv; ci = ti;
        }
    }

    double vd[NSEL];
#pragma unroll
    for (int j = 0; j < NSEL; ++j) vd[j] = (double)v[j];

    // mark ambiguous adjacent ranks
    int mk = 0;
#pragma unroll
    for (int i = 0; i < NSEL - 1; ++i)
        if (v[i] - v[i + 1] < EPS) mk |= (1 << i) | (1 << (i + 1));

    // rescue only if a rank that can affect output (0..7) is marked
    bool need = (mk & 0xFF) != 0;
    unsigned long long bal = __ballot(need);
    while (bal) {
        int t = __ffsll(bal) - 1; bal &= bal - 1;
        int tmk = __shfl(mk, t);
        const float* Xr = X + (size_t)(m0 + t) * DIM;
#pragma unroll
        for (int r = 0; r < NSEL; ++r) {
            if ((tmk >> r) & 1) {
                int e = __shfl(id[r], t);
                const float* Wr = W + (size_t)e * DIM;
                double s = 0.0;
#pragma unroll 4
                for (int i = 0; i < 16; ++i) {
                    float4 xx = *(const float4*)(Xr + i * 256 + lane * 4);
                    float4 ww = *(const float4*)(Wr + i * 256 + lane * 4);
                    s = fma((double)xx.x, (double)ww.x, s);
                    s = fma((double)xx.y, (double)ww.y, s);
                    s = fma((double)xx.z, (double)ww.z, s);
                    s = fma((double)xx.w, (double)ww.w, s);
                }
#pragma unroll
                for (int off = 1; off < 64; off <<= 1) s += __shfl_xor(s, off);
                s += (double)Bv[e];
                if (lane == t) vd[r] = s;
            }
        }
    }

    // re-sort marked-adjacent runs by fp64 value (desc), tie -> lower index
#pragma unroll 1
    for (int pass = 0; pass < NSEL; ++pass) {
#pragma unroll
        for (int i = 0; i < NSEL - 1; ++i) {
            if (((mk >> i) & 1) && ((mk >> (i + 1)) & 1)) {
                bool sw = (vd[i + 1] > vd[i]) || (vd[i + 1] == vd[i] && id[i + 1] < id[i]);
                double td = sw ? vd[i] : vd[i + 1];
                vd[i + 1] = sw ? vd[i + 1] * 0 + vd[i] : vd[i + 1];   // avoid, do explicit:
                if (sw) { vd[i + 1] = td; }                            // (td==vd[i])
                double ta = sw ? td : vd[i];                           // no-op keep
                (void)ta;
                if (sw) { double x0 = vd[i]; /* already moved */ (void)x0; }
            }
        }
    }
    // NOTE: the above got convoluted; do a clean bubble instead:
#pragma unroll 1
    for (int pass = 0; pass < NSEL; ++pass) {
#pragma unroll
        for (int i = 0; i < NSEL - 1; ++i) {
            if (((mk >> i) & 1) && ((mk >> (i + 1)) & 1)) {
                if ((vd[i + 1] > vd[i]) || (vd[i + 1] == vd[i] && id[i + 1] < id[i])) {
                    double td = vd[i]; vd[i] = vd[i + 1]; vd[i + 1] = td;
                    int ti = id[i]; id[i] = id[i + 1]; id[i + 1] = ti;
                }
            }
        }
    }

    // ---- softmax over top-8 + store ----
    float ex[TOPK]; float sum = 0.f;
    double mx = vd[0];
#pragma unroll
    for (int j = 0; j < TOPK; ++j) { ex[j] = expf((float)(vd[j] - mx)); sum += ex[j]; }
    float inv = 1.f / sum;

    const size_t o = (size_t)(m0 + lane) * TOPK;
    float4 p0 = { ex[0] * inv, ex[1] * inv, ex[2] * inv, ex[3] * inv };
    float4 p1 = { ex[4] * inv, ex[5] * inv, ex[6] * inv, ex[7] * inv };
    float4 i0 = { (float)id[0], (float)id[1], (float)id[2], (float)id[3] };
    float4 i1 = { (float)id[4], (float)id[5], (float)id[6], (float)id[7] };
    *(float4*)(outP + o)     = p0;
    *(float4*)(outP + o + 4) = p1;
    *(float4*)(outI + o)     = i0;
    *(float4*)(outI + o + 4) = i1;
}

extern "C" void kernel_launch(void* const* d_in, const int* in_sizes, int n_in,
                              void* d_out, int out_size, void* d_ws, size_t ws_size,
                              hipStream_t stream) {
    const float* X  = (const float*)d_in[0];
    const float* W  = (const float*)d_in[1];
    const float* Bv = (const float*)d_in[2];
    float* outP = (float*)d_out;
    float* outI = (float*)d_out + (size_t)NTOK * TOPK;

    dim3 grid(NTOK / MT);   // 256
    dim3 block(256);
    router_kernel<<<grid, block, 0, stream>>>(X, W, Bv, outP, outI);
}